// Round 1
// baseline (866.876 us; speedup 1.0000x reference)
//
#include <hip/hip_runtime.h>

// MaxUnpooling2D scatter-add — 4-channel / eighth-plane privatization.
// updates/mask: [32,64,64,128] f32/i32, out: [32,128,128,128] f32.
// out flat = (b<<21) | (bin<<7) | c  where bin = mask>>7 in [0,16384).
//
// R3 lesson: bottleneck was VMEM line-request rate -> float4/int4 accesses.
// R4 lesson (this round): at 64 KiB LDS only 2 blocks/CU are resident ->
//   (a) 8 waves/CU can't hide the 16B-granule load/store latency
//       (VALUBusy 2.25%, Occupancy 19.5%, HBM only 26% of peak);
//   (b) only half of each output line's 32 partner blocks are live at once,
//       so L2 evicts partially-dirty 512B lines (WRITE_SIZE 380MB vs 268
//       ideal -> masked HBM write bursts waste write BW).
// Fix: 8 passes x 2048 bins x 4ch = 32 KiB LDS -> 4 blocks/CU (128 KiB of
// 160), all 1024 blocks co-resident. Mask bins are packed to 16 bits so the
// register cache is 96 data VGPRs (u[16] float4 + pk[16] uint2), keeping
// total VGPRs <= 128 = the 16-waves/CU cap (launch_bounds enforces).
//
// XCD swizzle: b = bid&31 -> all 32 channel-group blocks of a batch share
// bid%8 (same XCD); they jointly cover each 512B input/output line, so L2
// serves one HBM fetch per line and merges 16B-dirty stores into full lines.
// With full co-residency the partners run phase-locked (identical work per
// pass), keeping each line's 32 deposits inside one L2 residency window.

#define HWC (64 * 64 * 128)   // 2^19 input elements per batch
#define PBINS 2048            // bins per pass (16 output rows x 128 x)
#define NPASS 8

__global__ __launch_bounds__(256, 4) void unpool_p8(
    const float* __restrict__ upd, const int* __restrict__ mask,
    float* __restrict__ out)
{
    __shared__ float acc[PBINS * 4];   // 32 KiB, layout [bin][4 channels]

    int bid = blockIdx.x;
    int b   = bid & 31;
    int c0  = (bid >> 5) << 2;         // channel group base, 0..124

    int t = threadIdx.x;

    const float4* ub = (const float4*)(upd  + (size_t)b * HWC + c0);
    const int4*   mb = (const int4*)  (mask + (size_t)b * HWC + c0);
    float*        ob = out + ((size_t)b << 21) + c0;

    // Register-cache this block's full input: 16 pos/thread.
    // u: 64 VGPRs; packed bins: 32 VGPRs (bin = mask>>7 < 16384 fits u16).
    float4 u[16];
    uint2  pk[16];
    #pragma unroll
    for (int k = 0; k < 16; ++k) {
        int pos = t + k * 256;         // (h,w) position 0..4095
        u[k] = ub[pos * 32];           // float4 stride = 128 floats
        int4 m4 = mb[pos * 32];
        unsigned b0 = ((unsigned)m4.x) >> 7;
        unsigned b1 = ((unsigned)m4.y) >> 7;
        unsigned b2 = ((unsigned)m4.z) >> 7;
        unsigned b3 = ((unsigned)m4.w) >> 7;
        pk[k].x = b0 | (b1 << 16);
        pk[k].y = b2 | (b3 << 16);
    }

    float4* a4 = (float4*)acc;

    for (int q = 0; q < NPASS; ++q) {
        // zero 32 KiB (8 float4 per thread)
        #pragma unroll
        for (int k = 0; k < 8; ++k)
            a4[t + k * 256] = make_float4(0.f, 0.f, 0.f, 0.f);
        __syncthreads();

        // scatter this pass's elements into LDS (ds_add, no return)
        unsigned uq = (unsigned)q;
        #pragma unroll
        for (int k = 0; k < 16; ++k) {
            unsigned b0 = pk[k].x & 0xffffu;
            unsigned b1 = pk[k].x >> 16;
            unsigned b2 = pk[k].y & 0xffffu;
            unsigned b3 = pk[k].y >> 16;
            if ((b0 >> 11) == uq) atomicAdd(&acc[((b0 & 2047u) << 2) + 0], u[k].x);
            if ((b1 >> 11) == uq) atomicAdd(&acc[((b1 & 2047u) << 2) + 1], u[k].y);
            if ((b2 >> 11) == uq) atomicAdd(&acc[((b2 & 2047u) << 2) + 2], u[k].z);
            if ((b3 >> 11) == uq) atomicAdd(&acc[((b3 & 2047u) << 2) + 3], u[k].w);
        }
        __syncthreads();

        // store the pass: out[b, bin, c0..c0+3] as float4, bin = q*2048+p
        #pragma unroll
        for (int k = 0; k < 8; ++k) {
            int p = t + k * 256;
            float4 v = a4[p];
            *(float4*)(ob + (size_t)(q * PBINS + p) * 128) = v;
        }
        if (q < NPASS - 1) __syncthreads();   // next pass rewrites acc
    }
}

extern "C" void kernel_launch(void* const* d_in, const int* in_sizes, int n_in,
                              void* d_out, int out_size, void* d_ws, size_t ws_size,
                              hipStream_t stream) {
    const float* upd  = (const float*)d_in[0];
    const int*   mask = (const int*)d_in[1];
    float*       out  = (float*)d_out;

    // 32 batches x 32 channel-groups; every output element written exactly
    // once -> no memset, no global atomics.
    unpool_p8<<<1024, 256, 0, stream>>>(upd, mask, out);
}

// Round 2
// 445.082 us; speedup vs baseline: 1.9477x; 1.9477x over previous
//
#include <hip/hip_runtime.h>

// MaxUnpooling2D scatter-add — 4-channel / quarter-plane privatization.
// updates/mask: [32,64,64,128] f32/i32, out: [32,128,128,128] f32.
// out flat = (b<<21) | (bin<<7) | c  where bin = mask>>7 in [0,16384).
//
// R3 lesson: bottleneck is VMEM line-request rate -> float4/int4 granules.
// R4 lesson: __launch_bounds__(256,4) capped VGPR at 128; the 96-VGPR
//   register cache spilled to scratch (VGPR_Count=64, FETCH 66->573MB,
//   WRITE 380->860MB, 3x slower). Occupancy DID double (19.5->41%) -> the
//   mechanism is right, the per-thread cache was too big for the cap.
// R5 fix: 512-thread blocks, 8 positions/thread. Data cache = u[8] (32
//   VGPR) + pk[8] (16 VGPR) = 48 VGPRs, comfortably under the 128-VGPR cap
//   of __launch_bounds__(512,4) -> no spill. LDS stays 64 KiB -> 2
//   blocks/CU, but 8 waves/block -> 16 waves/CU: 2x R3's latency hiding
//   with identical per-block work and traffic.
//
// XCD swizzle: b = bid&31 -> all 32 channel-group blocks of a batch share
// bid%8 (same XCD); they jointly cover each 512B input/output line, so L2
// serves one HBM fetch per line and merges 16B-dirty stores into full lines.

#define HWC (64 * 64 * 128)   // 2^19 input elements per batch
#define QBINS 4096            // bins per y-quarter (32 output rows x 128 x)

__global__ __launch_bounds__(512, 4) void unpool_q4w8(
    const float* __restrict__ upd, const int* __restrict__ mask,
    float* __restrict__ out)
{
    __shared__ float acc[QBINS * 4];   // 64 KiB, layout [bin][4 channels]

    int bid = blockIdx.x;
    int b   = bid & 31;
    int c0  = (bid >> 5) << 2;         // channel group base, 0..124

    int t = threadIdx.x;

    const float4* ub = (const float4*)(upd  + (size_t)b * HWC + c0);
    const int4*   mb = (const int4*)  (mask + (size_t)b * HWC + c0);
    float*        ob = out + ((size_t)b << 21) + c0;

    // Register-cache this block's full input: 8 pos/thread.
    // u: 32 VGPRs; packed bins: 16 VGPRs (bin = mask>>7 < 16384 fits u16).
    float4 u[8];
    uint2  pk[8];
    #pragma unroll
    for (int k = 0; k < 8; ++k) {
        int pos = t + k * 512;         // (h,w) position 0..4095
        u[k] = ub[pos * 32];           // float4 stride = 128 floats
        int4 m4 = mb[pos * 32];
        unsigned b0 = ((unsigned)m4.x) >> 7;
        unsigned b1 = ((unsigned)m4.y) >> 7;
        unsigned b2 = ((unsigned)m4.z) >> 7;
        unsigned b3 = ((unsigned)m4.w) >> 7;
        pk[k].x = b0 | (b1 << 16);
        pk[k].y = b2 | (b3 << 16);
    }

    float4* a4 = (float4*)acc;

    for (int q = 0; q < 4; ++q) {
        // zero 64 KiB (8 float4 per thread)
        #pragma unroll
        for (int k = 0; k < 8; ++k)
            a4[t + k * 512] = make_float4(0.f, 0.f, 0.f, 0.f);
        __syncthreads();

        // scatter this quarter's elements into LDS (ds_add, no return)
        unsigned uq = (unsigned)q;
        #pragma unroll
        for (int k = 0; k < 8; ++k) {
            unsigned b0 = pk[k].x & 0xffffu;
            unsigned b1 = pk[k].x >> 16;
            unsigned b2 = pk[k].y & 0xffffu;
            unsigned b3 = pk[k].y >> 16;
            if ((b0 >> 12) == uq) atomicAdd(&acc[((b0 & 4095u) << 2) + 0], u[k].x);
            if ((b1 >> 12) == uq) atomicAdd(&acc[((b1 & 4095u) << 2) + 1], u[k].y);
            if ((b2 >> 12) == uq) atomicAdd(&acc[((b2 & 4095u) << 2) + 2], u[k].z);
            if ((b3 >> 12) == uq) atomicAdd(&acc[((b3 & 4095u) << 2) + 3], u[k].w);
        }
        __syncthreads();

        // store the quarter: out[b, bin, c0..c0+3] as float4, bin = q*4096+p
        #pragma unroll
        for (int k = 0; k < 8; ++k) {
            int p = t + k * 512;
            float4 v = a4[p];
            *(float4*)(ob + (size_t)(q * QBINS + p) * 128) = v;
        }
        if (q < 3) __syncthreads();    // next pass rewrites acc
    }
}

extern "C" void kernel_launch(void* const* d_in, const int* in_sizes, int n_in,
                              void* d_out, int out_size, void* d_ws, size_t ws_size,
                              hipStream_t stream) {
    const float* upd  = (const float*)d_in[0];
    const int*   mask = (const int*)d_in[1];
    float*       out  = (float*)d_out;

    // 32 batches x 32 channel-groups; every output element written exactly
    // once -> no memset, no global atomics.
    unpool_q4w8<<<1024, 512, 0, stream>>>(upd, mask, out);
}